// Round 1
// baseline (749.224 us; speedup 1.0000x reference)
//
#include <hip/hip_runtime.h>

typedef __attribute__((ext_vector_type(4))) float f4;
typedef __attribute__((ext_vector_type(4))) float f32x4;
typedef __attribute__((ext_vector_type(8))) short short8;
typedef __attribute__((ext_vector_type(4))) unsigned int u32x4;

#define LDSB_STRIDE 2064          // bytes per Bt column: 1024 bf16 + 8 pad elems
#define LDS_BIAS_OFF 132096       // 64 * 2064
#define LDS_S_OFF 132352          // bias takes 256 B
#define LDS_S_PER_WAVE 1088       // 16 rows * 17 floats * 4 B
#define LDS_TOTAL 149760          // 132352 + 16 * 1088

__device__ __forceinline__ unsigned short f2bf(float f) {
  unsigned u = __builtin_bit_cast(unsigned, f);
  u += 0x7fffu + ((u >> 16) & 1u);          // RNE (inputs finite, no NaN path)
  return (unsigned short)(u >> 16);
}
__device__ __forceinline__ float bf2f(unsigned short h) {
  unsigned u = ((unsigned)h) << 16;
  return __builtin_bit_cast(float, u);
}
__device__ __forceinline__ float sigmoidf_(float v) {
  return 1.0f / (1.0f + __expf(-v));
}

// ---------------------------------------------------------------------------
// Prep: pack all 5 heads into Bt[64][1024] bf16 (column-major per head-col)
// cols 0-47 W_shs | 48-50 W_scaling | 51-53 W_xyz | 54 W_opacity |
// 55-58 bf16(W_rot) hi | 59-62 bf16(W_rot - hi) lo | 63 zero.
// Plus bias_f32[64] at byte offset 131072 of ws.
// ---------------------------------------------------------------------------
__global__ void gs_prep(const float* __restrict__ Wsh, const float* __restrict__ Wsc,
                        const float* __restrict__ Wxy, const float* __restrict__ Wop,
                        const float* __restrict__ Wro,
                        const float* __restrict__ bsh, const float* __restrict__ bsc,
                        const float* __restrict__ bxy, const float* __restrict__ bop,
                        const float* __restrict__ bro,
                        unsigned short* __restrict__ Bt, float* __restrict__ biasOut) {
  int idx = blockIdx.x * 256 + threadIdx.x;   // 0 .. 65535
  int c = idx >> 10, k = idx & 1023;
  float w;
  if (c < 48)       w = Wsh[k * 48 + c];
  else if (c < 51)  w = Wsc[k * 3 + (c - 48)];
  else if (c < 54)  w = Wxy[k * 3 + (c - 51)];
  else if (c == 54) w = Wop[k];
  else if (c < 59)  w = Wro[k * 4 + (c - 55)];
  else if (c < 63) {
    float orig = Wro[k * 4 + (c - 59)];
    w = orig - bf2f(f2bf(orig));              // residual for split-bf16 rotation
  } else w = 0.0f;
  Bt[c * 1024 + k] = f2bf(w);

  if (idx < 64) {
    int cc = idx; float b;
    if (cc < 48)       b = bsh[cc];
    else if (cc < 51)  b = bsc[cc - 48];
    else if (cc < 54)  b = bxy[cc - 51];
    else if (cc == 54) b = bop[0];
    else if (cc < 59)  b = bro[cc - 55];
    else               b = 0.0f;
    biasOut[cc] = b;
  }
}

// ---------------------------------------------------------------------------
// Main: 256 blocks x 1024 threads (16 waves), full B in LDS, no steady-state
// barriers. Each wave: 2 iterations x 16-row tile, K-loop of 32 steps,
// 5x mfma_f32_16x16x32_bf16 per step (4 head tiles + rotation correction).
// ---------------------------------------------------------------------------
__global__ __launch_bounds__(1024, 1) void gs_main(
    const float* __restrict__ x, const float* __restrict__ pts,
    const unsigned char* __restrict__ ws, float* __restrict__ out) {
  extern __shared__ __align__(16) unsigned char smem[];
  const int tid = threadIdx.x;
  const int wave = tid >> 6, lane = tid & 63;
  const int lane15 = lane & 15, quad = lane >> 4;

  // Stage Bt (128 KB, unpadded in ws) into LDS with +16 B/col padding.
  {
    const u32x4* src = (const u32x4*)ws;      // 8192 x 16 B
    for (int i = tid; i < 8192; i += 1024) {
      int c = i >> 7, k16 = i & 127;
      *(u32x4*)(smem + c * LDSB_STRIDE + (k16 << 4)) = src[i];
    }
    if (tid < 64)
      ((float*)(smem + LDS_BIAS_OFF))[tid] = ((const float*)(ws + 131072))[tid];
  }
  __syncthreads();

  const float* biasS = (const float*)(smem + LDS_BIAS_OFF);
  float* S = (float*)(smem + LDS_S_OFF + wave * LDS_S_PER_WAVE); // [16][17] f32

  const int gw = blockIdx.x * 16 + wave;      // 0..4095 global wave id
  for (int itr = 0; itr < 2; ++itr) {
    const int r0 = (itr * 4096 + gw) << 4;    // 16-row tile base
    const float* aptr = x + (size_t)(r0 + lane15) * 1024 + (quad << 3);
    f4 a0 = *(const f4*)aptr;
    f4 a1 = *(const f4*)(aptr + 4);

    f32x4 acc[4]; f32x4 accC;
    #pragma unroll
    for (int t = 0; t < 4; ++t) acc[t] = (f32x4){0.f, 0.f, 0.f, 0.f};
    accC = (f32x4){0.f, 0.f, 0.f, 0.f};

    #pragma unroll 4
    for (int kt = 0; kt < 32; ++kt) {
      f4 n0 = a0, n1 = a1;
      if (kt < 31) {
        const float* p = aptr + ((kt + 1) << 5);
        n0 = *(const f4*)p;
        n1 = *(const f4*)(p + 4);
      }
      // A fragments: hi bf16 + residual-lo bf16 (for rotation precision)
      short8 ah, al;
      #pragma unroll
      for (int j = 0; j < 4; ++j) {
        unsigned short h0 = f2bf(a0[j]);
        ah[j] = (short)h0;
        al[j] = (short)f2bf(a0[j] - bf2f(h0));
        unsigned short h1 = f2bf(a1[j]);
        ah[j + 4] = (short)h1;
        al[j + 4] = (short)f2bf(a1[j] - bf2f(h1));
      }
      const unsigned char* bb =
          smem + lane15 * LDSB_STRIDE + (kt << 6) + (quad << 4);
      short8 b0 = *(const short8*)(bb);
      short8 b1 = *(const short8*)(bb + 16 * LDSB_STRIDE);
      short8 b2 = *(const short8*)(bb + 32 * LDSB_STRIDE);
      short8 b3 = *(const short8*)(bb + 48 * LDSB_STRIDE);
      acc[0] = __builtin_amdgcn_mfma_f32_16x16x32_bf16(ah, b0, acc[0], 0, 0, 0);
      acc[1] = __builtin_amdgcn_mfma_f32_16x16x32_bf16(ah, b1, acc[1], 0, 0, 0);
      acc[2] = __builtin_amdgcn_mfma_f32_16x16x32_bf16(ah, b2, acc[2], 0, 0, 0);
      acc[3] = __builtin_amdgcn_mfma_f32_16x16x32_bf16(ah, b3, acc[3], 0, 0, 0);
      accC   = __builtin_amdgcn_mfma_f32_16x16x32_bf16(al, b3, accC,   0, 0, 0);
      a0 = n0; a1 = n1;
    }

    // Epilogue phase 1: shs cols 0-47 straight from accumulators (+bias).
    // C/D layout: col = lane&15, row = quad*4 + reg.
    const int rowb = r0 + (quad << 2);
    #pragma unroll
    for (int ct = 0; ct < 3; ++ct) {
      float bc = biasS[ct * 16 + lane15];
      #pragma unroll
      for (int i = 0; i < 4; ++i)
        out[(size_t)(rowb + i) * 62 + ct * 16 + lane15] = acc[ct][i] + bc;
    }

    // Phase 2: stage tile-3 (+ rotation correction acc) to per-wave LDS.
    #pragma unroll
    for (int i = 0; i < 4; ++i)
      S[((quad << 2) + i) * 17 + lane15] = acc[3][i] + accC[i];
    asm volatile("s_waitcnt lgkmcnt(0)" ::: "memory");

    // Phase 3: 16 rows x 14 output cols (48..61), cooperative across the wave.
    #pragma unroll
    for (int e = 0; e < 4; ++e) {
      int idx = e * 64 + lane;
      if (idx < 224) {
        int r = idx / 14;
        int j = idx - r * 14;
        const float* Sr = S + r * 17;
        float val;
        if (j < 3) {                      // scaling: clamp(exp(v), 0, 0.2)
          float v = Sr[j] + biasS[48 + j];
          val = fminf(fmaxf(__expf(v), 0.0f), 0.2f);
        } else if (j < 6) {               // offset
          float v = Sr[j] + biasS[48 + j];
          val = (sigmoidf_(v) - 0.5f) * 0.2f;
        } else if (j < 9) {               // xyz = pts + offset
          float v = Sr[j - 3] + biasS[45 + j];
          val = (sigmoidf_(v) - 0.5f) * 0.2f + pts[(size_t)(r0 + r) * 3 + (j - 6)];
        } else if (j == 9) {              // opacity
          val = sigmoidf_(Sr[6] + biasS[54]);
        } else {                          // rotation, split-bf16 compensated
          float q[4]; float ss = 0.0f;
          #pragma unroll
          for (int c = 0; c < 4; ++c) {
            q[c] = Sr[7 + c] + Sr[11 + c] + biasS[55 + c];
            ss += q[c] * q[c];
          }
          val = q[j - 10] / fmaxf(sqrtf(ss), 1e-12f);
        }
        out[(size_t)(r0 + r) * 62 + 48 + j] = val;
      }
    }
  }
}

extern "C" void kernel_launch(void* const* d_in, const int* in_sizes, int n_in,
                              void* d_out, int out_size, void* d_ws, size_t ws_size,
                              hipStream_t stream) {
  (void)in_sizes; (void)n_in; (void)out_size; (void)ws_size;
  const float* x   = (const float*)d_in[0];
  const float* pts = (const float*)d_in[1];
  const float* Wsh = (const float*)d_in[2];
  const float* bsh = (const float*)d_in[3];
  const float* Wsc = (const float*)d_in[4];
  const float* bsc = (const float*)d_in[5];
  const float* Wxy = (const float*)d_in[6];
  const float* bxy = (const float*)d_in[7];
  const float* Wop = (const float*)d_in[8];
  const float* bop = (const float*)d_in[9];
  const float* Wro = (const float*)d_in[10];
  const float* bro = (const float*)d_in[11];
  float* out = (float*)d_out;

  unsigned short* Bt = (unsigned short*)d_ws;
  float* biasOut = (float*)((char*)d_ws + 131072);

  gs_prep<<<256, 256, 0, stream>>>(Wsh, Wsc, Wxy, Wop, Wro,
                                   bsh, bsc, bxy, bop, bro, Bt, biasOut);

  (void)hipFuncSetAttribute((const void*)gs_main,
                            hipFuncAttributeMaxDynamicSharedMemorySize, LDS_TOTAL);
  gs_main<<<256, 1024, LDS_TOTAL, stream>>>(x, pts, (const unsigned char*)d_ws, out);
}

// Round 2
// 739.100 us; speedup vs baseline: 1.0137x; 1.0137x over previous
//
#include <hip/hip_runtime.h>

typedef __attribute__((ext_vector_type(4))) float f4;
typedef __attribute__((ext_vector_type(4))) float f32x4;
typedef __attribute__((ext_vector_type(8))) short short8;
typedef __attribute__((ext_vector_type(4))) unsigned int u32x4;

#define LDSB_STRIDE 2064          // bytes per Bt column: 1024 bf16 + 8 pad elems
#define LDS_BIAS_OFF 132096       // 64 * 2064
#define LDS_S_OFF 132352          // bias takes 256 B
#define LDS_S_PER_WAVE 1088       // 16 rows * 17 floats * 4 B
#define LDS_TOTAL 149760          // 132352 + 16 * 1088

__device__ __forceinline__ unsigned short f2bf(float f) {
  unsigned u = __builtin_bit_cast(unsigned, f);
  u += 0x7fffu + ((u >> 16) & 1u);          // RNE (inputs finite, no NaN path)
  return (unsigned short)(u >> 16);
}
__device__ __forceinline__ float bf2f(unsigned short h) {
  unsigned u = ((unsigned)h) << 16;
  return __builtin_bit_cast(float, u);
}
__device__ __forceinline__ float sigmoidf_(float v) {
  return 1.0f / (1.0f + __expf(-v));
}

// Split x into hi = bf16_rne(x) and lo = bf16_trunc(x - hi).
// hi: bfe + add3 + shr (~2-3 VALU); lo: and + sub + shr (~3 VALU); shifts
// pack-fold into v_perm for pairs. lo error <= 2^-17 |x| (only feeds the
// rotation-head correction MFMA).
__device__ __forceinline__ void split_bf(float f, unsigned short& hi,
                                         unsigned short& lo) {
  unsigned u = __builtin_bit_cast(unsigned, f);
  unsigned r = u + 0x7fffu + ((u >> 16) & 1u);
  hi = (unsigned short)(r >> 16);
  float hif = __builtin_bit_cast(float, r & 0xffff0000u);
  unsigned d = __builtin_bit_cast(unsigned, f - hif);
  lo = (unsigned short)(d >> 16);           // truncation is fine at 2^-17 level
}

// ---------------------------------------------------------------------------
// Prep: pack all 5 heads into Bt[64][1024] bf16 (column-major per head-col)
// cols 0-47 W_shs | 48-50 W_scaling | 51-53 W_xyz | 54 W_opacity |
// 55-58 bf16(W_rot) hi | 59-62 bf16(W_rot - hi) lo | 63 zero.
// Plus bias_f32[64] at byte offset 131072 of ws.
// ---------------------------------------------------------------------------
__global__ void gs_prep(const float* __restrict__ Wsh, const float* __restrict__ Wsc,
                        const float* __restrict__ Wxy, const float* __restrict__ Wop,
                        const float* __restrict__ Wro,
                        const float* __restrict__ bsh, const float* __restrict__ bsc,
                        const float* __restrict__ bxy, const float* __restrict__ bop,
                        const float* __restrict__ bro,
                        unsigned short* __restrict__ Bt, float* __restrict__ biasOut) {
  int idx = blockIdx.x * 256 + threadIdx.x;   // 0 .. 65535
  int c = idx >> 10, k = idx & 1023;
  float w;
  if (c < 48)       w = Wsh[k * 48 + c];
  else if (c < 51)  w = Wsc[k * 3 + (c - 48)];
  else if (c < 54)  w = Wxy[k * 3 + (c - 51)];
  else if (c == 54) w = Wop[k];
  else if (c < 59)  w = Wro[k * 4 + (c - 55)];
  else if (c < 63) {
    float orig = Wro[k * 4 + (c - 59)];
    w = orig - bf2f(f2bf(orig));              // residual for split-bf16 rotation
  } else w = 0.0f;
  Bt[c * 1024 + k] = f2bf(w);

  if (idx < 64) {
    int cc = idx; float b;
    if (cc < 48)       b = bsh[cc];
    else if (cc < 51)  b = bsc[cc - 48];
    else if (cc < 54)  b = bxy[cc - 51];
    else if (cc == 54) b = bop[0];
    else if (cc < 59)  b = bro[cc - 55];
    else               b = 0.0f;
    biasOut[cc] = b;
  }
}

// ---------------------------------------------------------------------------
// Main: 256 blocks x 1024 threads (16 waves), full B in LDS, no steady-state
// barriers. Each wave: 2 iterations x 16-row tile, fully-unrolled K-loop of
// 32 steps with prefetch distance 4 (8 dwordx4 in flight per wave),
// 5x mfma_f32_16x16x32_bf16 per step (4 head tiles + rotation correction).
// ---------------------------------------------------------------------------
__global__ __launch_bounds__(1024, 1) void gs_main(
    const float* __restrict__ x, const float* __restrict__ pts,
    const unsigned char* __restrict__ ws, float* __restrict__ out) {
  extern __shared__ __align__(16) unsigned char smem[];
  const int tid = threadIdx.x;
  const int wave = tid >> 6, lane = tid & 63;
  const int lane15 = lane & 15, quad = lane >> 4;

  // Stage Bt (128 KB, unpadded in ws) into LDS with +16 B/col padding.
  {
    const u32x4* src = (const u32x4*)ws;      // 8192 x 16 B
    for (int i = tid; i < 8192; i += 1024) {
      int c = i >> 7, k16 = i & 127;
      *(u32x4*)(smem + c * LDSB_STRIDE + (k16 << 4)) = src[i];
    }
    if (tid < 64)
      ((float*)(smem + LDS_BIAS_OFF))[tid] = ((const float*)(ws + 131072))[tid];
  }
  __syncthreads();

  const float* biasS = (const float*)(smem + LDS_BIAS_OFF);
  float* S = (float*)(smem + LDS_S_OFF + wave * LDS_S_PER_WAVE); // [16][17] f32

  const int gw = blockIdx.x * 16 + wave;      // 0..4095 global wave id
  for (int itr = 0; itr < 2; ++itr) {
    const int r0 = (itr * 4096 + gw) << 4;    // 16-row tile base
    const float* aptr = x + (size_t)(r0 + lane15) * 1024 + (quad << 3);

    // 5-slot rotating prefetch buffer, distance 4 K-steps.
    f4 buf[5][2];
    #pragma unroll
    for (int p = 0; p < 4; ++p) {
      buf[p][0] = *(const f4*)(aptr + (p << 5));
      buf[p][1] = *(const f4*)(aptr + (p << 5) + 4);
    }

    f32x4 acc[4]; f32x4 accC;
    #pragma unroll
    for (int t = 0; t < 4; ++t) acc[t] = (f32x4){0.f, 0.f, 0.f, 0.f};
    accC = (f32x4){0.f, 0.f, 0.f, 0.f};

    #pragma unroll
    for (int kt = 0; kt < 32; ++kt) {
      if (kt + 4 < 32) {                      // static after full unroll
        const float* p = aptr + ((kt + 4) << 5);
        buf[(kt + 4) % 5][0] = *(const f4*)p;
        buf[(kt + 4) % 5][1] = *(const f4*)(p + 4);
      }
      f4 a0 = buf[kt % 5][0];
      f4 a1 = buf[kt % 5][1];

      short8 ah, al;
      #pragma unroll
      for (int j = 0; j < 4; ++j) {
        unsigned short h, l;
        split_bf(a0[j], h, l); ah[j] = (short)h; al[j] = (short)l;
        split_bf(a1[j], h, l); ah[j + 4] = (short)h; al[j + 4] = (short)l;
      }

      const unsigned char* bb =
          smem + lane15 * LDSB_STRIDE + (kt << 6) + (quad << 4);
      short8 b0 = *(const short8*)(bb);
      short8 b1 = *(const short8*)(bb + 16 * LDSB_STRIDE);
      short8 b2 = *(const short8*)(bb + 32 * LDSB_STRIDE);
      short8 b3 = *(const short8*)(bb + 48 * LDSB_STRIDE);
      acc[0] = __builtin_amdgcn_mfma_f32_16x16x32_bf16(ah, b0, acc[0], 0, 0, 0);
      acc[1] = __builtin_amdgcn_mfma_f32_16x16x32_bf16(ah, b1, acc[1], 0, 0, 0);
      acc[2] = __builtin_amdgcn_mfma_f32_16x16x32_bf16(ah, b2, acc[2], 0, 0, 0);
      acc[3] = __builtin_amdgcn_mfma_f32_16x16x32_bf16(ah, b3, acc[3], 0, 0, 0);
      accC   = __builtin_amdgcn_mfma_f32_16x16x32_bf16(al, b3, accC,   0, 0, 0);
    }

    // Epilogue phase 1: shs cols 0-47 straight from accumulators (+bias).
    // C/D layout: col = lane&15, row = quad*4 + reg.
    const int rowb = r0 + (quad << 2);
    #pragma unroll
    for (int ct = 0; ct < 3; ++ct) {
      float bc = biasS[ct * 16 + lane15];
      #pragma unroll
      for (int i = 0; i < 4; ++i)
        out[(size_t)(rowb + i) * 62 + ct * 16 + lane15] = acc[ct][i] + bc;
    }

    // Phase 2: stage tile-3 (+ rotation correction acc) to per-wave LDS.
    #pragma unroll
    for (int i = 0; i < 4; ++i)
      S[((quad << 2) + i) * 17 + lane15] = acc[3][i] + accC[i];
    asm volatile("s_waitcnt lgkmcnt(0)" ::: "memory");

    // Phase 3: 16 rows x 14 output cols (48..61), cooperative across the wave.
    #pragma unroll
    for (int e = 0; e < 4; ++e) {
      int idx = e * 64 + lane;
      if (idx < 224) {
        int r = idx / 14;
        int j = idx - r * 14;
        const float* Sr = S + r * 17;
        float val;
        if (j < 3) {                      // scaling: clamp(exp(v), 0, 0.2)
          float v = Sr[j] + biasS[48 + j];
          val = fminf(fmaxf(__expf(v), 0.0f), 0.2f);
        } else if (j < 6) {               // offset
          float v = Sr[j] + biasS[48 + j];
          val = (sigmoidf_(v) - 0.5f) * 0.2f;
        } else if (j < 9) {               // xyz = pts + offset
          float v = Sr[j - 3] + biasS[45 + j];
          val = (sigmoidf_(v) - 0.5f) * 0.2f + pts[(size_t)(r0 + r) * 3 + (j - 6)];
        } else if (j == 9) {              // opacity
          val = sigmoidf_(Sr[6] + biasS[54]);
        } else {                          // rotation, split-bf16 compensated
          float q[4]; float ss = 0.0f;
          #pragma unroll
          for (int c = 0; c < 4; ++c) {
            q[c] = Sr[7 + c] + Sr[11 + c] + biasS[55 + c];
            ss += q[c] * q[c];
          }
          val = q[j - 10] / fmaxf(sqrtf(ss), 1e-12f);
        }
        out[(size_t)(r0 + r) * 62 + 48 + j] = val;
      }
    }
  }
}

extern "C" void kernel_launch(void* const* d_in, const int* in_sizes, int n_in,
                              void* d_out, int out_size, void* d_ws, size_t ws_size,
                              hipStream_t stream) {
  (void)in_sizes; (void)n_in; (void)out_size; (void)ws_size;
  const float* x   = (const float*)d_in[0];
  const float* pts = (const float*)d_in[1];
  const float* Wsh = (const float*)d_in[2];
  const float* bsh = (const float*)d_in[3];
  const float* Wsc = (const float*)d_in[4];
  const float* bsc = (const float*)d_in[5];
  const float* Wxy = (const float*)d_in[6];
  const float* bxy = (const float*)d_in[7];
  const float* Wop = (const float*)d_in[8];
  const float* bop = (const float*)d_in[9];
  const float* Wro = (const float*)d_in[10];
  const float* bro = (const float*)d_in[11];
  float* out = (float*)d_out;

  unsigned short* Bt = (unsigned short*)d_ws;
  float* biasOut = (float*)((char*)d_ws + 131072);

  gs_prep<<<256, 256, 0, stream>>>(Wsh, Wsc, Wxy, Wop, Wro,
                                   bsh, bsc, bxy, bop, bro, Bt, biasOut);

  (void)hipFuncSetAttribute((const void*)gs_main,
                            hipFuncAttributeMaxDynamicSharedMemorySize, LDS_TOTAL);
  gs_main<<<256, 1024, LDS_TOTAL, stream>>>(x, pts, (const unsigned char*)d_ws, out);
}